// Round 5
// baseline (166.407 us; speedup 1.0000x reference)
//
#include <hip/hip_runtime.h>

#define H     256
#define BM    64
#define NTHR  512
#define LDK2  264    // 256 + 8 pad (ushorts): row stride 528 B

typedef __attribute__((ext_vector_type(4))) float f32x4;
typedef __attribute__((ext_vector_type(8))) short bf16x8;

__device__ __forceinline__ ushort f2bf(float f) {
    union { float f; unsigned u; } v; v.f = f;
    unsigned u = v.u;
    unsigned r = (u + 0x7fffu + ((u >> 16) & 1u)) >> 16;
    return (ushort)r;
}
__device__ __forceinline__ float bf2f(ushort h) {
    union { unsigned u; float f; } v; v.u = ((unsigned)h) << 16;
    return v.f;
}
__device__ __forceinline__ float sigmoid_f(float x) {
    return __builtin_amdgcn_rcpf(1.0f + __expf(-x));
}
__device__ __forceinline__ float tanh_f(float x) {
    float ax = fabsf(x);
    float e  = __expf(-2.0f * ax);
    float t  = (1.0f - e) * __builtin_amdgcn_rcpf(1.0f + e);
    return copysignf(t, x);
}

// --- weight prep: f32 [k][n] -> bf16 panels [n][k] in d_ws ---
// rows 0..255 = r cols (k<256: W_r, k>=256: U_r); 256..511 = z; 512..767 = h
__global__ void prep_w(const float* __restrict__ Wr, const float* __restrict__ Wz,
                       const float* __restrict__ Wh, const float* __restrict__ Ur,
                       const float* __restrict__ Uz, const float* __restrict__ Uh,
                       ushort* __restrict__ P)
{
    const int k  = blockIdx.x;          // 0..511
    const int kk = k & 255;
    const bool hi = k >= 256;
    for (int n = threadIdx.x; n < 768; n += 256) {
        float v;
        if (n < 256)      v = (hi ? Ur : Wr)[kk * 256 + n];
        else if (n < 512) v = (hi ? Uz : Wz)[kk * 256 + (n - 256)];
        else              v = (hi ? Uh : Wh)[kk * 256 + (n - 512)];
        P[(size_t)n * 512 + k] = f2bf(v);
    }
}

__device__ __forceinline__ void stage256(const float* __restrict__ src, size_t r0,
                                         int tid, ushort* __restrict__ sb)
{
    #pragma unroll
    for (int i = 0; i < 8; ++i) {
        const int c   = tid + i * NTHR;     // 0..4095 over (row, f4-chunk)
        const int row = c >> 6;
        const int c4  = (c & 63) * 4;
        const f32x4 v = *(const f32x4*)(src + (r0 + row) * H + c4);
        ushort4 w;
        w.x = f2bf(v[0]); w.y = f2bf(v[1]); w.z = f2bf(v[2]); w.w = f2bf(v[3]);
        *(ushort4*)&sb[row * LDK2 + c4] = w;
    }
}

__global__ __launch_bounds__(NTHR, 4)
void gru_main(const float* __restrict__ joint, const float* __restrict__ mgn,
              const ushort* __restrict__ P,
              const float* __restrict__ br_, const float* __restrict__ bz_,
              const float* __restrict__ bh_, float* __restrict__ out)
{
    __shared__ ushort sb[BM * LDK2];    // one K-half (256 cols) of A, bf16

    const int tid  = threadIdx.x;
    const int wave = tid >> 6;          // 0..7
    const int lane = tid & 63;
    const int l15  = lane & 15;
    const int kq   = lane >> 4;         // 0..3
    const int colbase = wave * 32;      // this wave's 32-col slice (same for r,z,h)
    const size_t r0 = (size_t)blockIdx.x * BM;

    float br[2], bz[2], bh[2];
    #pragma unroll
    for (int j = 0; j < 2; ++j) {
        const int c = colbase + j * 16 + l15;
        br[j] = br_[c]; bz[j] = bz_[c]; bh[j] = bh_[c];
    }

    // per-wave B base pointers (row = colbase + j*16 + l15; +kq*8 within row)
    const ushort* __restrict__ pBr = P + (size_t)(colbase + l15) * 512 + kq * 8;
    const ushort* __restrict__ pBz = pBr + (size_t)256 * 512;
    const ushort* __restrict__ pBh = pBr + (size_t)512 * 512;

    // --- phase 1: r|z accumulation over two K-halves ---
    f32x4 aR[4][2], aZ[4][2];
    #pragma unroll
    for (int i = 0; i < 4; ++i)
        #pragma unroll
        for (int j = 0; j < 2; ++j) {
            aR[i][j] = (f32x4){0.f, 0.f, 0.f, 0.f};
            aZ[i][j] = (f32x4){0.f, 0.f, 0.f, 0.f};
        }

    #pragma unroll 1
    for (int half = 0; half < 2; ++half) {
        __syncthreads();                 // previous readers done
        stage256(half == 0 ? mgn : joint, r0, tid, sb);
        __syncthreads();
        const int koff = half * 256;
        #pragma unroll 4
        for (int k0 = 0; k0 < 256; k0 += 32) {
            bf16x8 bR[2], bZ[2], af[4];
            #pragma unroll
            for (int j = 0; j < 2; ++j) {
                bR[j] = *(const bf16x8*)(pBr + (size_t)j * 16 * 512 + koff + k0);
                bZ[j] = *(const bf16x8*)(pBz + (size_t)j * 16 * 512 + koff + k0);
            }
            #pragma unroll
            for (int i = 0; i < 4; ++i)
                af[i] = *(const bf16x8*)&sb[(i * 16 + l15) * LDK2 + k0 + kq * 8];
            #pragma unroll
            for (int j = 0; j < 2; ++j)
                #pragma unroll
                for (int i = 0; i < 4; ++i) {
                    aR[i][j] = __builtin_amdgcn_mfma_f32_16x16x32_bf16(af[i], bR[j], aR[i][j], 0, 0, 0);
                    aZ[i][j] = __builtin_amdgcn_mfma_f32_16x16x32_bf16(af[i], bZ[j], aZ[i][j], 0, 0, 0);
                }
        }
    }
    __syncthreads();   // all waves done reading joint half

    // --- gates: z in regs; a = joint*r overwrites joint in LDS ---
    #pragma unroll
    for (int i = 0; i < 4; ++i)
        #pragma unroll
        for (int j = 0; j < 2; ++j)
            #pragma unroll
            for (int q = 0; q < 4; ++q) {
                const int row = i * 16 + kq * 4 + q;
                const int c   = colbase + j * 16 + l15;
                const float r = sigmoid_f(aR[i][j][q] + br[j]);
                const float hj = bf2f(sb[row * LDK2 + c]);
                sb[row * LDK2 + c] = f2bf(hj * r);
                aZ[i][j][q] = sigmoid_f(aZ[i][j][q] + bz[j]);
            }
    __syncthreads();

    // --- phase 2: ht = [mgn | a] @ P2; do a-half (k 256..511) first ---
    f32x4 aH[4][2];
    #pragma unroll
    for (int i = 0; i < 4; ++i)
        #pragma unroll
        for (int j = 0; j < 2; ++j)
            aH[i][j] = (f32x4){0.f, 0.f, 0.f, 0.f};

    #pragma unroll 1
    for (int half = 1; half >= 0; --half) {     // half=1: a (already in LDS); half=0: mgn re-stage
        if (half == 0) {
            __syncthreads();
            stage256(mgn, r0, tid, sb);
            __syncthreads();
        }
        const int koff = half * 256;
        #pragma unroll 4
        for (int k0 = 0; k0 < 256; k0 += 32) {
            bf16x8 bH[2], af[4];
            #pragma unroll
            for (int j = 0; j < 2; ++j)
                bH[j] = *(const bf16x8*)(pBh + (size_t)j * 16 * 512 + koff + k0);
            #pragma unroll
            for (int i = 0; i < 4; ++i)
                af[i] = *(const bf16x8*)&sb[(i * 16 + l15) * LDK2 + k0 + kq * 8];
            #pragma unroll
            for (int j = 0; j < 2; ++j)
                #pragma unroll
                for (int i = 0; i < 4; ++i)
                    aH[i][j] = __builtin_amdgcn_mfma_f32_16x16x32_bf16(af[i], bH[j], aH[i][j], 0, 0, 0);
        }
    }

    // --- epilogue: out = ht + z*(h - ht), h re-read f32 ---
    #pragma unroll
    for (int i = 0; i < 4; ++i)
        #pragma unroll
        for (int j = 0; j < 2; ++j)
            #pragma unroll
            for (int q = 0; q < 4; ++q) {
                const int row = i * 16 + kq * 4 + q;
                const int c   = colbase + j * 16 + l15;
                const float ht = tanh_f(aH[i][j][q] + bh[j]);
                const float z  = aZ[i][j][q];
                const float h  = joint[(r0 + row) * H + c];
                out[(r0 + row) * H + c] = ht + z * (h - ht);
            }
}

extern "C" void kernel_launch(void* const* d_in, const int* in_sizes, int n_in,
                              void* d_out, int out_size, void* d_ws, size_t ws_size,
                              hipStream_t stream)
{
    const float* joint = (const float*)d_in[0];
    const float* mgn   = (const float*)d_in[1];
    const float* Wr    = (const float*)d_in[2];
    const float* Wz    = (const float*)d_in[3];
    const float* Wh    = (const float*)d_in[4];
    const float* Ur    = (const float*)d_in[5];
    const float* Uz    = (const float*)d_in[6];
    const float* Uh    = (const float*)d_in[7];
    const float* br    = (const float*)d_in[8];
    const float* bz    = (const float*)d_in[9];
    const float* bh    = (const float*)d_in[10];

    ushort* P  = (ushort*)d_ws;          // 786 KB scratch
    float* out = (float*)d_out;

    prep_w<<<512, 256, 0, stream>>>(Wr, Wz, Wh, Ur, Uz, Uh, P);

    const int nrows = 65536;
    gru_main<<<nrows / BM, NTHR, 0, stream>>>(joint, mgn, P, br, bz, bh, out);
}

// Round 6
// 105.231 us; speedup vs baseline: 1.5814x; 1.5814x over previous
//
#include <hip/hip_runtime.h>

#define H     256
#define BM    128
#define NTHR  512
#define LDK2  264    // 256 + 8 pad (ushorts): row stride 528 B

typedef __attribute__((ext_vector_type(4))) float f32x4;
typedef __attribute__((ext_vector_type(8))) short bf16x8;

__device__ __forceinline__ ushort f2bf(float f) {
    union { float f; unsigned u; } v; v.f = f;
    unsigned u = v.u;
    unsigned r = (u + 0x7fffu + ((u >> 16) & 1u)) >> 16;
    return (ushort)r;
}
__device__ __forceinline__ float bf2f(ushort h) {
    union { unsigned u; float f; } v; v.u = ((unsigned)h) << 16;
    return v.f;
}
__device__ __forceinline__ float sigmoid_f(float x) {
    return __builtin_amdgcn_rcpf(1.0f + __expf(-x));
}
__device__ __forceinline__ float tanh_f(float x) {
    float ax = fabsf(x);
    float e  = __expf(-2.0f * ax);
    float t  = (1.0f - e) * __builtin_amdgcn_rcpf(1.0f + e);
    return copysignf(t, x);
}

// --- weight prep: f32 [k][n] -> bf16 panels [n][k] in d_ws ---
// rows 0..255 = r cols (k<256: W_r, k>=256: U_r); 256..511 = z; 512..767 = h
__global__ void prep_w(const float* __restrict__ Wr, const float* __restrict__ Wz,
                       const float* __restrict__ Wh, const float* __restrict__ Ur,
                       const float* __restrict__ Uz, const float* __restrict__ Uh,
                       ushort* __restrict__ P)
{
    const int k  = blockIdx.x;          // 0..511
    const int kk = k & 255;
    const bool hi = k >= 256;
    for (int n = threadIdx.x; n < 768; n += 256) {
        float v;
        if (n < 256)      v = (hi ? Ur : Wr)[kk * 256 + n];
        else if (n < 512) v = (hi ? Uz : Wz)[kk * 256 + (n - 256)];
        else              v = (hi ? Uh : Wh)[kk * 256 + (n - 512)];
        P[(size_t)n * 512 + k] = f2bf(v);
    }
}

#define MFMA(a, b, c) __builtin_amdgcn_mfma_f32_16x16x32_bf16((a), (b), (c), 0, 0, 0)

// one 16x16x32 k-step over r|z accumulators
#define RZ_STEP(SB, KOFF, K0) do {                                            \
    bf16x8 bR_[2], bZ_[2], af_[8];                                            \
    _Pragma("unroll") for (int j_ = 0; j_ < 2; ++j_) {                        \
        bR_[j_] = *(const bf16x8*)(pBr + (size_t)j_ * 16 * 512 + (KOFF) + (K0)); \
        bZ_[j_] = *(const bf16x8*)(pBz + (size_t)j_ * 16 * 512 + (KOFF) + (K0)); \
    }                                                                         \
    _Pragma("unroll") for (int i_ = 0; i_ < 8; ++i_)                          \
        af_[i_] = *(const bf16x8*)&SB[(i_ * 16 + l15) * LDK2 + (K0) + kq * 8];\
    _Pragma("unroll") for (int j_ = 0; j_ < 2; ++j_)                          \
    _Pragma("unroll") for (int i_ = 0; i_ < 8; ++i_) {                        \
        aR[i_][j_] = MFMA(af_[i_], bR_[j_], aR[i_][j_]);                      \
        aZ[i_][j_] = MFMA(af_[i_], bZ_[j_], aZ[i_][j_]);                      \
    }                                                                         \
} while (0)

#define H_STEP(SB, KOFF, K0) do {                                             \
    bf16x8 bH_[2], af_[8];                                                    \
    _Pragma("unroll") for (int j_ = 0; j_ < 2; ++j_)                          \
        bH_[j_] = *(const bf16x8*)(pBh + (size_t)j_ * 16 * 512 + (KOFF) + (K0)); \
    _Pragma("unroll") for (int i_ = 0; i_ < 8; ++i_)                          \
        af_[i_] = *(const bf16x8*)&SB[(i_ * 16 + l15) * LDK2 + (K0) + kq * 8];\
    _Pragma("unroll") for (int j_ = 0; j_ < 2; ++j_)                          \
    _Pragma("unroll") for (int i_ = 0; i_ < 8; ++i_)                          \
        aH[i_][j_] = MFMA(af_[i_], bH_[j_], aH[i_][j_]);                      \
} while (0)

__global__ __launch_bounds__(NTHR, 2)
void gru_main(const float* __restrict__ joint, const float* __restrict__ mgn,
              const ushort* __restrict__ P,
              const float* __restrict__ br_, const float* __restrict__ bz_,
              const float* __restrict__ bh_, float* __restrict__ out)
{
    __shared__ ushort sb0[BM * LDK2];   // mgn bf16 — resident for the whole kernel
    __shared__ ushort sb1[BM * LDK2];   // joint bf16 -> overwritten by a = joint*r

    const int tid  = threadIdx.x;
    const int wave = tid >> 6;          // 0..7
    const int lane = tid & 63;
    const int l15  = lane & 15;
    const int kq   = lane >> 4;         // 0..3
    const int colbase = wave * 32;
    const size_t r0 = (size_t)blockIdx.x * BM;

    float br[2], bz[2], bh[2];
    #pragma unroll
    for (int j = 0; j < 2; ++j) {
        const int c = colbase + j * 16 + l15;
        br[j] = br_[c]; bz[j] = bz_[c]; bh[j] = bh_[c];
    }

    const ushort* __restrict__ pBr = P + (size_t)(colbase + l15) * 512 + kq * 8;
    const ushort* __restrict__ pBz = pBr + (size_t)256 * 512;
    const ushort* __restrict__ pBh = pBr + (size_t)512 * 512;

    // --- stage 0: mgn -> sb0 (kernel head, nothing to overlap with) ---
    #pragma unroll
    for (int i = 0; i < 16; ++i) {
        const int c   = tid + i * NTHR;
        const int row = c >> 6;
        const int c4  = (c & 63) * 4;
        const f32x4 v = *(const f32x4*)(mgn + (r0 + row) * H + c4);
        ushort4 w;
        w.x = f2bf(v[0]); w.y = f2bf(v[1]); w.z = f2bf(v[2]); w.w = f2bf(v[3]);
        *(ushort4*)&sb0[row * LDK2 + c4] = w;
    }
    __syncthreads();

    f32x4 aR[8][2], aZ[8][2];
    #pragma unroll
    for (int i = 0; i < 8; ++i)
        #pragma unroll
        for (int j = 0; j < 2; ++j) {
            aR[i][j] = (f32x4){0.f, 0.f, 0.f, 0.f};
            aZ[i][j] = (f32x4){0.f, 0.f, 0.f, 0.f};
        }

    // --- phase 1, k-half 0 (mgn in sb0), pipelined with joint -> sb1 staging ---
    {
        f32x4 jv[8];
        // issue chunk 0 (rows 0..63)
        #pragma unroll
        for (int i = 0; i < 8; ++i) {
            const int c = tid + i * NTHR;
            jv[i] = *(const f32x4*)(joint + (r0 + (c >> 6)) * H + (c & 63) * 4);
        }
        #pragma unroll
        for (int k0 = 0; k0 < 128; k0 += 32) RZ_STEP(sb0, 0, k0);
        // commit chunk 0
        #pragma unroll
        for (int i = 0; i < 8; ++i) {
            const int c   = tid + i * NTHR;
            const int row = c >> 6;
            const int c4  = (c & 63) * 4;
            ushort4 w;
            w.x = f2bf(jv[i][0]); w.y = f2bf(jv[i][1]);
            w.z = f2bf(jv[i][2]); w.w = f2bf(jv[i][3]);
            *(ushort4*)&sb1[row * LDK2 + c4] = w;
        }
        // issue chunk 1 (rows 64..127)
        #pragma unroll
        for (int i = 0; i < 8; ++i) {
            const int c = tid + (i + 8) * NTHR;
            jv[i] = *(const f32x4*)(joint + (r0 + (c >> 6)) * H + (c & 63) * 4);
        }
        #pragma unroll
        for (int k0 = 128; k0 < 256; k0 += 32) RZ_STEP(sb0, 0, k0);
        // commit chunk 1
        #pragma unroll
        for (int i = 0; i < 8; ++i) {
            const int c   = tid + (i + 8) * NTHR;
            const int row = c >> 6;
            const int c4  = (c & 63) * 4;
            ushort4 w;
            w.x = f2bf(jv[i][0]); w.y = f2bf(jv[i][1]);
            w.z = f2bf(jv[i][2]); w.w = f2bf(jv[i][3]);
            *(ushort4*)&sb1[row * LDK2 + c4] = w;
        }
    }
    __syncthreads();

    // --- phase 1, k-half 1 (joint in sb1) ---
    #pragma unroll 4
    for (int k0 = 0; k0 < 256; k0 += 32) RZ_STEP(sb1, 256, k0);
    __syncthreads();

    // --- gates: z in regs; a = joint*r overwrites sb1 ---
    #pragma unroll
    for (int i = 0; i < 8; ++i)
        #pragma unroll
        for (int j = 0; j < 2; ++j)
            #pragma unroll
            for (int q = 0; q < 4; ++q) {
                const int row = i * 16 + kq * 4 + q;
                const int c   = colbase + j * 16 + l15;
                const float r = sigmoid_f(aR[i][j][q] + br[j]);
                const float hj = bf2f(sb1[row * LDK2 + c]);
                sb1[row * LDK2 + c] = f2bf(hj * r);
                aZ[i][j][q] = sigmoid_f(aZ[i][j][q] + bz[j]);
            }
    __syncthreads();

    // --- phase 2: ht = [mgn | a] @ P_h — both halves resident, no staging ---
    f32x4 aH[8][2];
    #pragma unroll
    for (int i = 0; i < 8; ++i)
        #pragma unroll
        for (int j = 0; j < 2; ++j)
            aH[i][j] = (f32x4){0.f, 0.f, 0.f, 0.f};

    #pragma unroll 4
    for (int k0 = 0; k0 < 256; k0 += 32) H_STEP(sb1, 256, k0);
    #pragma unroll 4
    for (int k0 = 0; k0 < 256; k0 += 32) H_STEP(sb0, 0, k0);

    // --- epilogue: out = ht + z*(h - ht), h re-read f32 (L3-warm) ---
    #pragma unroll
    for (int i = 0; i < 8; ++i)
        #pragma unroll
        for (int j = 0; j < 2; ++j)
            #pragma unroll
            for (int q = 0; q < 4; ++q) {
                const int row = i * 16 + kq * 4 + q;
                const int c   = colbase + j * 16 + l15;
                const float ht = tanh_f(aH[i][j][q] + bh[j]);
                const float z  = aZ[i][j][q];
                const float h  = joint[(r0 + row) * H + c];
                out[(r0 + row) * H + c] = ht + z * (h - ht);
            }
}

extern "C" void kernel_launch(void* const* d_in, const int* in_sizes, int n_in,
                              void* d_out, int out_size, void* d_ws, size_t ws_size,
                              hipStream_t stream)
{
    const float* joint = (const float*)d_in[0];
    const float* mgn   = (const float*)d_in[1];
    const float* Wr    = (const float*)d_in[2];
    const float* Wz    = (const float*)d_in[3];
    const float* Wh    = (const float*)d_in[4];
    const float* Ur    = (const float*)d_in[5];
    const float* Uz    = (const float*)d_in[6];
    const float* Uh    = (const float*)d_in[7];
    const float* br    = (const float*)d_in[8];
    const float* bz    = (const float*)d_in[9];
    const float* bh    = (const float*)d_in[10];

    ushort* P  = (ushort*)d_ws;          // 786 KB scratch
    float* out = (float*)d_out;

    prep_w<<<512, 256, 0, stream>>>(Wr, Wz, Wh, Ur, Uz, Uh, P);

    const int nrows = 65536;
    gru_main<<<nrows / BM, NTHR, 0, stream>>>(joint, mgn, P, br, bz, bh, out);
}